// Round 1
// baseline (653.034 us; speedup 1.0000x reference)
//
#include <hip/hip_runtime.h>

// z: [16,4096,256] fp32 -> N=65536 rows, d=256
// embedding: [256,1024], cluster_size: [1024], embedding_mean: [256,1024]

#define DECAYC 0.99f
#define EPSQ 1e-5f

typedef unsigned short ushort_t;
typedef __attribute__((ext_vector_type(8))) short bf16x8;
typedef __attribute__((ext_vector_type(16))) float f32x16;
typedef unsigned long long u64;

__device__ __forceinline__ ushort_t f2bf(float x) {
    unsigned u = __float_as_uint(x);
    unsigned r = (u + 0x7FFFu + ((u >> 16) & 1u)) >> 16;   // RNE
    return (ushort_t)r;
}
__device__ __forceinline__ float bf2f(ushort_t h) {
    return __uint_as_float(((unsigned)h) << 16);
}
__device__ __forceinline__ u64 umin64(u64 a, u64 b) { return a < b ? a : b; }

// ---------------- E-side prep (fused): ET + colnorm + Eph/Epl + zero stats ----------------
__global__ __launch_bounds__(256) void prep_E_kernel(const float* __restrict__ E,
                                                     float* __restrict__ ET,
                                                     float* __restrict__ colnorm,
                                                     ushort_t* __restrict__ Eph,
                                                     ushort_t* __restrict__ Epl,
                                                     int* __restrict__ counts,
                                                     float* __restrict__ lossSum) {
    int n = blockIdx.x;
    int d = threadIdx.x;
    if (d == 0) counts[n] = 0;
    if (n == 0 && d == 1) lossSum[0] = 0.f;
    float v = E[d * 1024 + n];
    ET[n * 256 + d] = v;
    ushort_t h = f2bf(v);
    ushort_t l = f2bf(v - bf2f(h));
    size_t pi = ((size_t)(d >> 3) * 1024 + n) * 8 + (d & 7);
    Eph[pi] = h;
    Epl[pi] = l;
    __shared__ float red[256];
    red[d] = v * v;
    __syncthreads();
    for (int o = 128; o > 0; o >>= 1) {
        if (d < o) red[d] += red[d + o];
        __syncthreads();
    }
    if (d == 0) colnorm[n] = red[0];
}

// ---------------- MFMA distance + argmin + fused gather/loss/hist ----------------
// Round-8 restructure: 512 thr = 8 waves as (wrow 2) x (wcol 4); each wave owns one
// 32x32 tile per 128-code chunk using v_mfma_f32_32x32x16_bf16 (ceiling 2495 vs
// 2075 TF, half the MFMA instruction count). Same 68KB A-tile LDS -> still
// 2 blocks/CU, but 16 waves/CU = 4 waves/SIMD (was 2) for latency hiding.
// Argmin: float-compare + cndmask of cb index per accumulator reg (4 VALU/cand
// vs 9 for packed-u64); sortable-u64 pack once at the end (tie -> lowest code).
__global__ __launch_bounds__(512, 4) void dist_mfma_kernel(const float* __restrict__ z,
                                                           const ushort_t* __restrict__ Eph,
                                                           const ushort_t* __restrict__ Epl,
                                                           const float* __restrict__ colnorm,
                                                           const float* __restrict__ ET,
                                                           float* __restrict__ out0,
                                                           float* __restrict__ lossSum,
                                                           int* __restrict__ counts,
                                                           int* __restrict__ idxOut) {
    __shared__ __align__(16) ushort_t Ah[16384];   // slots (kq*64+r)*8, 32 KB
    __shared__ __align__(16) ushort_t Al[16384];
    __shared__ u64 bl[4][64];                      // per-wcol row minima
    __shared__ float zpart[8][64];                 // per-wave ||z||^2 partials
    __shared__ int kArr[64];

    const int t = threadIdx.x;
    const int lane = t & 63;
    const int w = t >> 6;          // wave 0..7
    const int wrow = w >> 2;       // 0..1 (rows wrow*32..)
    const int wcol = w & 3;        // 0..3 (codes wcol*32.. within 128-chunk)
    const int l31 = lane & 31;
    const int h = lane >> 5;       // k-block half
    const int rowBase = blockIdx.x * 64;

    // ---- one-time: convert 64 z rows to bf16 hi/lo in LDS + ||z||^2 partials ----
    float zsq = 0.f;
#pragma unroll
    for (int i = 0; i < 4; ++i) {
        int s = i * 512 + t;       // slot: kq = s>>6, r = s&63 (== lane)
        int kq = s >> 6;
        int r = s & 63;
        const float* gp = z + (size_t)(rowBase + r) * 256 + kq * 8;
        float4 v0 = *(const float4*)gp;
        float4 v1 = *(const float4*)(gp + 4);
        float vv[8] = {v0.x, v0.y, v0.z, v0.w, v1.x, v1.y, v1.z, v1.w};
        ushort_t hh[8], ll[8];
#pragma unroll
        for (int j = 0; j < 8; ++j) {
            hh[j] = f2bf(vv[j]);
            ll[j] = f2bf(vv[j] - bf2f(hh[j]));
            zsq += vv[j] * vv[j];
        }
        ushort4 h0 = {hh[0], hh[1], hh[2], hh[3]}, h1 = {hh[4], hh[5], hh[6], hh[7]};
        ushort4 l0 = {ll[0], ll[1], ll[2], ll[3]}, l1 = {ll[4], ll[5], ll[6], ll[7]};
        *(ushort4*)&Ah[s * 8] = h0;
        *(ushort4*)&Ah[s * 8 + 4] = h1;
        *(ushort4*)&Al[s * 8] = l0;
        *(ushort4*)&Al[s * 8 + 4] = l1;
    }
    zpart[w][lane] = zsq;
    __syncthreads();

    float bv[16];
    int bc[16];
#pragma unroll
    for (int reg = 0; reg < 16; ++reg) {
        bv[reg] = __builtin_inff();
        bc[reg] = 0;
    }

    for (int cb = 0; cb < 8; ++cb) {
        const int code = cb * 128 + wcol * 32 + l31;
        f32x16 acc;
#pragma unroll
        for (int reg = 0; reg < 16; ++reg) acc[reg] = 0.f;

#pragma unroll
        for (int ks = 0; ks < 16; ++ks) {
            const int kq = ks * 2 + h;                       // 0..31
            const size_t bbase = ((size_t)kq * 1024 + code) * 8;
            bf16x8 bfh = *(const bf16x8*)(Eph + bbase);
            bf16x8 bfl = *(const bf16x8*)(Epl + bbase);
            const int ao = (kq * 64 + wrow * 32 + l31) * 8;
            bf16x8 afh = *(const bf16x8*)&Ah[ao];
            bf16x8 afl = *(const bf16x8*)&Al[ao];
            acc = __builtin_amdgcn_mfma_f32_32x32x16_bf16(afh, bfh, acc, 0, 0, 0);
            acc = __builtin_amdgcn_mfma_f32_32x32x16_bf16(afh, bfl, acc, 0, 0, 0);
            acc = __builtin_amdgcn_mfma_f32_32x32x16_bf16(afl, bfh, acc, 0, 0, 0);
        }

        // lane-local argmin update: dist = cn - 2*dot (+||z||^2 added at the end)
        const float cn = colnorm[code];
#pragma unroll
        for (int reg = 0; reg < 16; ++reg) {
            float dist = cn - 2.f * acc[reg];
            bool lt = dist < bv[reg];
            bv[reg] = lt ? dist : bv[reg];
            bc[reg] = lt ? cb : bc[reg];
        }
    }

    // one-time: sortable pack + cross-lane min within each 32-lane half
#pragma unroll
    for (int reg = 0; reg < 16; ++reg) {
        unsigned fb = __float_as_uint(bv[reg]);
        unsigned sk = (fb & 0x80000000u) ? ~fb : (fb | 0x80000000u);
        unsigned code = (unsigned)(bc[reg] * 128 + wcol * 32 + l31);
        u64 b = ((u64)sk << 32) | code;
        b = umin64(b, __shfl_xor(b, 1, 64));
        b = umin64(b, __shfl_xor(b, 2, 64));
        b = umin64(b, __shfl_xor(b, 4, 64));
        b = umin64(b, __shfl_xor(b, 8, 64));
        b = umin64(b, __shfl_xor(b, 16, 64));
        if (l31 == 0) {
            int r = (reg & 3) + 8 * (reg >> 2) + 4 * h;      // C-row within 32-tile
            bl[wcol][wrow * 32 + r] = b;
        }
    }
    __syncthreads();

    // ---- epilogue: merge wcol quarters, decode key -> code + loss, hist ----
    if (t < 64) {
        u64 b = umin64(umin64(bl[0][t], bl[1][t]), umin64(bl[2][t], bl[3][t]));
        int k = (int)(unsigned)(b & 0xFFFFFFFFull);
        unsigned sk = (unsigned)(b >> 32);
        unsigned fb = (sk & 0x80000000u) ? (sk ^ 0x80000000u) : ~sk;
        float zn = 0.f;
#pragma unroll
        for (int wv = 0; wv < 8; ++wv) zn += zpart[wv][t];
        float dmin = __uint_as_float(fb) + zn;
        idxOut[rowBase + t] = k;
        kArr[t] = k;
        atomicAdd(counts + k, 1);
        float v = dmin;
#pragma unroll
        for (int o = 32; o > 0; o >>= 1) v += __shfl_down(v, o, 64);
        if (t == 0) atomicAdd(lossSum, v);
    }
    __syncthreads();

    // ---- gather z_q: wave w writes rows w*8..w*8+7 (no z re-read) ----
#pragma unroll
    for (int i = 0; i < 8; ++i) {
        int r = w * 8 + i;
        int k = kArr[r];
        float4 qv = *(const float4*)(ET + (size_t)k * 256 + lane * 4);
        *(float4*)(out0 + (size_t)(rowBase + r) * 256 + lane * 4) = qv;
    }
}

// ---------------- prefix scan + cluster_size_new + n + loss finalize ----------------
__global__ __launch_bounds__(1024) void prefix_csn_kernel(const int* __restrict__ counts,
                                                          const float* __restrict__ cluster_size,
                                                          const float* __restrict__ lossSum,
                                                          int* __restrict__ offsets,
                                                          int* __restrict__ cursor,
                                                          float* __restrict__ out3,
                                                          float* __restrict__ out1,
                                                          float* __restrict__ nOut) {
    __shared__ int sbuf[1024];
    int t = threadIdx.x;
    int c = counts[t];
    sbuf[t] = c;
    __syncthreads();
    for (int off = 1; off < 1024; off <<= 1) {
        int v = (t >= off) ? sbuf[t - off] : 0;
        __syncthreads();
        sbuf[t] += v;
        __syncthreads();
    }
    offsets[t] = sbuf[t] - c;
    if (t == 1023) offsets[1024] = sbuf[1023];
    cursor[t] = 0;

    float cn = cluster_size[t] * DECAYC + (1.f - DECAYC) * (float)c;
    out3[t] = cn;
    float v = cn;
#pragma unroll
    for (int o = 32; o > 0; o >>= 1) v += __shfl_down(v, o, 64);
    __shared__ float fbuf[16];
    int lane = t & 63, wv = t >> 6;
    if (lane == 0) fbuf[wv] = v;
    __syncthreads();
    if (t == 0) {
        float n = 0.f;
#pragma unroll
        for (int i = 0; i < 16; ++i) n += fbuf[i];
        nOut[0] = n;
        out1[0] = 0.25f * lossSum[0] / 16777216.0f;
    }
}

// ---------------- scatter row ids into code-sorted order ----------------
__global__ __launch_bounds__(256) void scatter_sort_kernel(const int* __restrict__ idx,
                                                           const int* __restrict__ offsets,
                                                           int* __restrict__ cursor,
                                                           int* __restrict__ sorted) {
    int i = blockIdx.x * 256 + threadIdx.x;
    int k = idx[i];
    int pos = atomicAdd(cursor + k, 1);
    sorted[offsets[k] + pos] = i;
}

// ---------------- segmented sum: psum[(k*8+s)*256+d] (no atomics) ----------------
__global__ __launch_bounds__(256) void segsum_kernel(const float* __restrict__ z,
                                                     const int* __restrict__ sorted,
                                                     const int* __restrict__ offsets,
                                                     float* __restrict__ psum) {
    const int k = blockIdx.x >> 3;
    const int s = blockIdx.x & 7;
    const int t = threadIdx.x;
    const int lane = t & 63;
    const int w = t >> 6;
    const int start = offsets[k], end = offsets[k + 1];
    float4 acc = {0.f, 0.f, 0.f, 0.f};
    for (int j = start + s * 4 + w; j < end; j += 32) {
        int row = sorted[j];
        float4 v = *(const float4*)(z + (size_t)row * 256 + lane * 4);
        acc.x += v.x; acc.y += v.y; acc.z += v.z; acc.w += v.w;
    }
    __shared__ float red[4][256];
    *(float4*)&red[w][lane * 4] = acc;
    __syncthreads();
    float v = red[0][t] + red[1][t] + red[2][t] + red[3][t];
    psum[((size_t)k * 8 + s) * 256 + t] = v;
}

// ---------------- embedding_mean_new + embedding_new ----------------
__global__ __launch_bounds__(256) void final8_kernel(const float* __restrict__ embedding_mean,
                                                     const float* __restrict__ psum,
                                                     const float* __restrict__ csn,
                                                     const float* __restrict__ nPtr,
                                                     float* __restrict__ out2,
                                                     float* __restrict__ out4) {
    int tid = blockIdx.x * 256 + threadIdx.x;
    int d = tid >> 10;
    int k = tid & 1023;
    const float* p = psum + (size_t)k * 8 * 256 + d;
    float es = 0.f;
#pragma unroll
    for (int s = 0; s < 8; ++s) es += p[s * 256];
    float emn = embedding_mean[tid] * DECAYC + (1.f - DECAYC) * es;
    out4[tid] = emn;
    float n = nPtr[0];
    float c = csn[k];
    float cs = (c + EPSQ) / (n + 1024.f * EPSQ) * n;
    out2[tid] = emn / cs;
}

extern "C" void kernel_launch(void* const* d_in, const int* in_sizes, int n_in,
                              void* d_out, int out_size, void* d_ws, size_t ws_size,
                              hipStream_t stream) {
    const float* z = (const float*)d_in[0];
    const float* E = (const float*)d_in[1];
    const float* cluster_size = (const float*)d_in[2];
    const float* embedding_mean = (const float*)d_in[3];

    float* out0 = (float*)d_out;        // z_q_st
    float* out1 = out0 + 16777216;      // vq_loss
    float* out2 = out1 + 1;             // embedding_new
    float* out3 = out2 + 262144;        // cluster_size_new
    float* out4 = out3 + 1024;          // embedding_mean_new

    // ws layout (float units)
    float* ws = (float*)d_ws;
    float* colnorm = ws;                         // 1024
    int* idx = (int*)(ws + 1024);                // 65536
    int* counts = (int*)(ws + 66560);            // 1024  (zeroed in prep_E)
    float* lossSum = ws + 67584;                 // 1     (zeroed in prep_E)
    float* nOut = ws + 67585;                    // 1
    float* ET = ws + 67588;                      // 262144 fp32 [k][d]
    ushort_t* Eph = (ushort_t*)(ws + 329732);    // 262144 ushort
    ushort_t* Epl = (ushort_t*)(ws + 460804);    // 262144 ushort
    float* psum = ws + 591876;                   // 2097152
    int* sorted = (int*)(ws + 2689028);          // 65536
    int* offsets = (int*)(ws + 2754564);         // 1025
    int* cursor = (int*)(ws + 2755592);          // 1024

    prep_E_kernel<<<1024, 256, 0, stream>>>(E, ET, colnorm, Eph, Epl, counts, lossSum);
    dist_mfma_kernel<<<1024, 512, 0, stream>>>(z, Eph, Epl, colnorm, ET,
                                               out0, lossSum, counts, idx);
    prefix_csn_kernel<<<1, 1024, 0, stream>>>(counts, cluster_size, lossSum,
                                              offsets, cursor, out3, out1, nOut);
    scatter_sort_kernel<<<256, 256, 0, stream>>>(idx, offsets, cursor, sorted);
    segsum_kernel<<<8192, 256, 0, stream>>>(z, sorted, offsets, psum);
    final8_kernel<<<1024, 256, 0, stream>>>(embedding_mean, psum, out3, nOut, out2, out4);
}

// Round 2
// 405.579 us; speedup vs baseline: 1.6101x; 1.6101x over previous
//
#include <hip/hip_runtime.h>

// z: [16,4096,256] fp32 -> N=65536 rows, d=256
// embedding: [256,1024], cluster_size: [1024], embedding_mean: [256,1024]

#define DECAYC 0.99f
#define EPSQ 1e-5f

typedef unsigned short ushort_t;
typedef __attribute__((ext_vector_type(8))) short bf16x8;
typedef __attribute__((ext_vector_type(16))) float f32x16;
typedef unsigned long long u64;

__device__ __forceinline__ ushort_t f2bf(float x) {
    unsigned u = __float_as_uint(x);
    unsigned r = (u + 0x7FFFu + ((u >> 16) & 1u)) >> 16;   // RNE
    return (ushort_t)r;
}
__device__ __forceinline__ float bf2f(ushort_t h) {
    return __uint_as_float(((unsigned)h) << 16);
}
__device__ __forceinline__ u64 umin64(u64 a, u64 b) { return a < b ? a : b; }

// ---------------- E-side prep (fused): ET + colnorm + Eph/Epl + zero stats ----------------
__global__ __launch_bounds__(256) void prep_E_kernel(const float* __restrict__ E,
                                                     float* __restrict__ ET,
                                                     float* __restrict__ colnorm,
                                                     ushort_t* __restrict__ Eph,
                                                     ushort_t* __restrict__ Epl,
                                                     int* __restrict__ counts,
                                                     float* __restrict__ lossSum) {
    int n = blockIdx.x;
    int d = threadIdx.x;
    if (d == 0) counts[n] = 0;
    if (n == 0 && d == 1) lossSum[0] = 0.f;
    float v = E[d * 1024 + n];
    ET[n * 256 + d] = v;
    ushort_t h = f2bf(v);
    ushort_t l = f2bf(v - bf2f(h));
    size_t pi = ((size_t)(d >> 3) * 1024 + n) * 8 + (d & 7);
    Eph[pi] = h;
    Epl[pi] = l;
    __shared__ float red[256];
    red[d] = v * v;
    __syncthreads();
    for (int o = 128; o > 0; o >>= 1) {
        if (d < o) red[d] += red[d + o];
        __syncthreads();
    }
    if (d == 0) colnorm[n] = red[0];
}

// ---------------- MFMA distance + argmin + fused gather/loss/hist ----------------
// Round-9: same 512-thr / 32x32x16 structure as round-8 (verified correct) but
// spill-fixed. Round-8 post-mortem: __launch_bounds__(512,4) => VGPR cap 64
// (observed allocator rule: cap ~= 256/arg2) => catastrophic scratch spill
// (FETCH 50MB->1GB). Fix: (512,2) => cap 256, and shrink argmin state 48->16
// regs by packing (sortable_dist & ~7)|cb into one u32 per acc reg so the
// allocator lands <=128 VGPR and LDS (70KB, 2 blocks/CU) stays the occupancy
// limiter at 16 waves/CU = 4 waves/SIMD.
__global__ __launch_bounds__(512, 2) void dist_mfma_kernel(const float* __restrict__ z,
                                                           const ushort_t* __restrict__ Eph,
                                                           const ushort_t* __restrict__ Epl,
                                                           const float* __restrict__ colnorm,
                                                           const float* __restrict__ ET,
                                                           float* __restrict__ out0,
                                                           float* __restrict__ lossSum,
                                                           int* __restrict__ counts,
                                                           int* __restrict__ idxOut) {
    __shared__ __align__(16) ushort_t Ah[16384];   // slots (kq*64+r)*8, 32 KB
    __shared__ __align__(16) ushort_t Al[16384];
    __shared__ u64 bl[4][64];                      // per-wcol row minima
    __shared__ float zpart[8][64];                 // per-wave ||z||^2 partials
    __shared__ int kArr[64];

    const int t = threadIdx.x;
    const int lane = t & 63;
    const int w = t >> 6;          // wave 0..7
    const int wrow = w >> 2;       // 0..1 (rows wrow*32..)
    const int wcol = w & 3;        // 0..3 (codes wcol*32.. within 128-chunk)
    const int l31 = lane & 31;
    const int h = lane >> 5;       // k-block half
    const int rowBase = blockIdx.x * 64;

    // ---- one-time: convert 64 z rows to bf16 hi/lo in LDS + ||z||^2 partials ----
    float zsq = 0.f;
#pragma unroll
    for (int i = 0; i < 4; ++i) {
        int s = i * 512 + t;       // slot: kq = s>>6, r = s&63 (== lane)
        int kq = s >> 6;
        int r = s & 63;
        const float* gp = z + (size_t)(rowBase + r) * 256 + kq * 8;
        float4 v0 = *(const float4*)gp;
        float4 v1 = *(const float4*)(gp + 4);
        float vv[8] = {v0.x, v0.y, v0.z, v0.w, v1.x, v1.y, v1.z, v1.w};
        ushort_t hh[8], ll[8];
#pragma unroll
        for (int j = 0; j < 8; ++j) {
            hh[j] = f2bf(vv[j]);
            ll[j] = f2bf(vv[j] - bf2f(hh[j]));
            zsq += vv[j] * vv[j];
        }
        ushort4 h0 = {hh[0], hh[1], hh[2], hh[3]}, h1 = {hh[4], hh[5], hh[6], hh[7]};
        ushort4 l0 = {ll[0], ll[1], ll[2], ll[3]}, l1 = {ll[4], ll[5], ll[6], ll[7]};
        *(ushort4*)&Ah[s * 8] = h0;
        *(ushort4*)&Ah[s * 8 + 4] = h1;
        *(ushort4*)&Al[s * 8] = l0;
        *(ushort4*)&Al[s * 8 + 4] = l1;
    }
    zpart[w][lane] = zsq;
    __syncthreads();

    // argmin state: one sortable u32 per acc reg.
    // key = (sortable(dist) & ~7) | cb ; umin => min dist, tie -> lowest cb.
    unsigned bestk[16];
#pragma unroll
    for (int reg = 0; reg < 16; ++reg) bestk[reg] = 0xFFFFFFFFu;

    for (int cb = 0; cb < 8; ++cb) {
        const int code = cb * 128 + wcol * 32 + l31;
        f32x16 acc;
#pragma unroll
        for (int reg = 0; reg < 16; ++reg) acc[reg] = 0.f;

#pragma unroll
        for (int ks = 0; ks < 16; ++ks) {
            const int kq = ks * 2 + h;                       // 0..31
            const size_t bbase = ((size_t)kq * 1024 + code) * 8;
            bf16x8 bfh = *(const bf16x8*)(Eph + bbase);
            bf16x8 bfl = *(const bf16x8*)(Epl + bbase);
            const int ao = (kq * 64 + wrow * 32 + l31) * 8;
            bf16x8 afh = *(const bf16x8*)&Ah[ao];
            bf16x8 afl = *(const bf16x8*)&Al[ao];
            acc = __builtin_amdgcn_mfma_f32_32x32x16_bf16(afh, bfh, acc, 0, 0, 0);
            acc = __builtin_amdgcn_mfma_f32_32x32x16_bf16(afh, bfl, acc, 0, 0, 0);
            acc = __builtin_amdgcn_mfma_f32_32x32x16_bf16(afl, bfh, acc, 0, 0, 0);
        }

        // lane-local argmin update: dist = cn - 2*dot (+||z||^2 added at the end)
        const float cn = colnorm[code];
#pragma unroll
        for (int reg = 0; reg < 16; ++reg) {
            float dist = cn - 2.f * acc[reg];
            unsigned fb = __float_as_uint(dist);
            unsigned sk = (fb & 0x80000000u) ? ~fb : (fb | 0x80000000u);
            unsigned key = (sk & 0xFFFFFFF8u) | (unsigned)cb;
            bestk[reg] = key < bestk[reg] ? key : bestk[reg];
        }
    }

    // one-time: expand to u64 (dist|code) + cross-lane min within each 32-lane half
#pragma unroll
    for (int reg = 0; reg < 16; ++reg) {
        unsigned key = bestk[reg];
        unsigned code = (key & 7u) * 128u + (unsigned)(wcol * 32 + l31);
        u64 b = ((u64)(key & 0xFFFFFFF8u) << 32) | code;
        b = umin64(b, __shfl_xor(b, 1, 64));
        b = umin64(b, __shfl_xor(b, 2, 64));
        b = umin64(b, __shfl_xor(b, 4, 64));
        b = umin64(b, __shfl_xor(b, 8, 64));
        b = umin64(b, __shfl_xor(b, 16, 64));
        if (l31 == 0) {
            int r = (reg & 3) + 8 * (reg >> 2) + 4 * h;      // C-row within 32-tile
            bl[wcol][wrow * 32 + r] = b;
        }
    }
    __syncthreads();

    // ---- epilogue: merge wcol quarters, decode key -> code + loss, hist ----
    if (t < 64) {
        u64 b = umin64(umin64(bl[0][t], bl[1][t]), umin64(bl[2][t], bl[3][t]));
        int k = (int)(unsigned)(b & 0xFFFFFFFFull);
        unsigned sk = (unsigned)(b >> 32);
        unsigned fb = (sk & 0x80000000u) ? (sk ^ 0x80000000u) : ~sk;
        float zn = 0.f;
#pragma unroll
        for (int wv = 0; wv < 8; ++wv) zn += zpart[wv][t];
        float dmin = __uint_as_float(fb) + zn;
        idxOut[rowBase + t] = k;
        kArr[t] = k;
        atomicAdd(counts + k, 1);
        float v = dmin;
#pragma unroll
        for (int o = 32; o > 0; o >>= 1) v += __shfl_down(v, o, 64);
        if (t == 0) atomicAdd(lossSum, v);
    }
    __syncthreads();

    // ---- gather z_q: wave w writes rows w*8..w*8+7 (no z re-read) ----
#pragma unroll
    for (int i = 0; i < 8; ++i) {
        int r = w * 8 + i;
        int k = kArr[r];
        float4 qv = *(const float4*)(ET + (size_t)k * 256 + lane * 4);
        *(float4*)(out0 + (size_t)(rowBase + r) * 256 + lane * 4) = qv;
    }
}

// ---------------- prefix scan + cluster_size_new + n + loss finalize ----------------
__global__ __launch_bounds__(1024) void prefix_csn_kernel(const int* __restrict__ counts,
                                                          const float* __restrict__ cluster_size,
                                                          const float* __restrict__ lossSum,
                                                          int* __restrict__ offsets,
                                                          int* __restrict__ cursor,
                                                          float* __restrict__ out3,
                                                          float* __restrict__ out1,
                                                          float* __restrict__ nOut) {
    __shared__ int sbuf[1024];
    int t = threadIdx.x;
    int c = counts[t];
    sbuf[t] = c;
    __syncthreads();
    for (int off = 1; off < 1024; off <<= 1) {
        int v = (t >= off) ? sbuf[t - off] : 0;
        __syncthreads();
        sbuf[t] += v;
        __syncthreads();
    }
    offsets[t] = sbuf[t] - c;
    if (t == 1023) offsets[1024] = sbuf[1023];
    cursor[t] = 0;

    float cn = cluster_size[t] * DECAYC + (1.f - DECAYC) * (float)c;
    out3[t] = cn;
    float v = cn;
#pragma unroll
    for (int o = 32; o > 0; o >>= 1) v += __shfl_down(v, o, 64);
    __shared__ float fbuf[16];
    int lane = t & 63, wv = t >> 6;
    if (lane == 0) fbuf[wv] = v;
    __syncthreads();
    if (t == 0) {
        float n = 0.f;
#pragma unroll
        for (int i = 0; i < 16; ++i) n += fbuf[i];
        nOut[0] = n;
        out1[0] = 0.25f * lossSum[0] / 16777216.0f;
    }
}

// ---------------- scatter row ids into code-sorted order ----------------
__global__ __launch_bounds__(256) void scatter_sort_kernel(const int* __restrict__ idx,
                                                           const int* __restrict__ offsets,
                                                           int* __restrict__ cursor,
                                                           int* __restrict__ sorted) {
    int i = blockIdx.x * 256 + threadIdx.x;
    int k = idx[i];
    int pos = atomicAdd(cursor + k, 1);
    sorted[offsets[k] + pos] = i;
}

// ---------------- segmented sum: psum[(k*8+s)*256+d] (no atomics) ----------------
__global__ __launch_bounds__(256) void segsum_kernel(const float* __restrict__ z,
                                                     const int* __restrict__ sorted,
                                                     const int* __restrict__ offsets,
                                                     float* __restrict__ psum) {
    const int k = blockIdx.x >> 3;
    const int s = blockIdx.x & 7;
    const int t = threadIdx.x;
    const int lane = t & 63;
    const int w = t >> 6;
    const int start = offsets[k], end = offsets[k + 1];
    float4 acc = {0.f, 0.f, 0.f, 0.f};
    for (int j = start + s * 4 + w; j < end; j += 32) {
        int row = sorted[j];
        float4 v = *(const float4*)(z + (size_t)row * 256 + lane * 4);
        acc.x += v.x; acc.y += v.y; acc.z += v.z; acc.w += v.w;
    }
    __shared__ float red[4][256];
    *(float4*)&red[w][lane * 4] = acc;
    __syncthreads();
    float v = red[0][t] + red[1][t] + red[2][t] + red[3][t];
    psum[((size_t)k * 8 + s) * 256 + t] = v;
}

// ---------------- embedding_mean_new + embedding_new ----------------
__global__ __launch_bounds__(256) void final8_kernel(const float* __restrict__ embedding_mean,
                                                     const float* __restrict__ psum,
                                                     const float* __restrict__ csn,
                                                     const float* __restrict__ nPtr,
                                                     float* __restrict__ out2,
                                                     float* __restrict__ out4) {
    int tid = blockIdx.x * 256 + threadIdx.x;
    int d = tid >> 10;
    int k = tid & 1023;
    const float* p = psum + (size_t)k * 8 * 256 + d;
    float es = 0.f;
#pragma unroll
    for (int s = 0; s < 8; ++s) es += p[s * 256];
    float emn = embedding_mean[tid] * DECAYC + (1.f - DECAYC) * es;
    out4[tid] = emn;
    float n = nPtr[0];
    float c = csn[k];
    float cs = (c + EPSQ) / (n + 1024.f * EPSQ) * n;
    out2[tid] = emn / cs;
}

extern "C" void kernel_launch(void* const* d_in, const int* in_sizes, int n_in,
                              void* d_out, int out_size, void* d_ws, size_t ws_size,
                              hipStream_t stream) {
    const float* z = (const float*)d_in[0];
    const float* E = (const float*)d_in[1];
    const float* cluster_size = (const float*)d_in[2];
    const float* embedding_mean = (const float*)d_in[3];

    float* out0 = (float*)d_out;        // z_q_st
    float* out1 = out0 + 16777216;      // vq_loss
    float* out2 = out1 + 1;             // embedding_new
    float* out3 = out2 + 262144;        // cluster_size_new
    float* out4 = out3 + 1024;          // embedding_mean_new

    // ws layout (float units)
    float* ws = (float*)d_ws;
    float* colnorm = ws;                         // 1024
    int* idx = (int*)(ws + 1024);                // 65536
    int* counts = (int*)(ws + 66560);            // 1024  (zeroed in prep_E)
    float* lossSum = ws + 67584;                 // 1     (zeroed in prep_E)
    float* nOut = ws + 67585;                    // 1
    float* ET = ws + 67588;                      // 262144 fp32 [k][d]
    ushort_t* Eph = (ushort_t*)(ws + 329732);    // 262144 ushort
    ushort_t* Epl = (ushort_t*)(ws + 460804);    // 262144 ushort
    float* psum = ws + 591876;                   // 2097152
    int* sorted = (int*)(ws + 2689028);          // 65536
    int* offsets = (int*)(ws + 2754564);         // 1025
    int* cursor = (int*)(ws + 2755592);          // 1024

    prep_E_kernel<<<1024, 256, 0, stream>>>(E, ET, colnorm, Eph, Epl, counts, lossSum);
    dist_mfma_kernel<<<1024, 512, 0, stream>>>(z, Eph, Epl, colnorm, ET,
                                               out0, lossSum, counts, idx);
    prefix_csn_kernel<<<1, 1024, 0, stream>>>(counts, cluster_size, lossSum,
                                              offsets, cursor, out3, out1, nOut);
    scatter_sort_kernel<<<256, 256, 0, stream>>>(idx, offsets, cursor, sorted);
    segsum_kernel<<<8192, 256, 0, stream>>>(z, sorted, offsets, psum);
    final8_kernel<<<1024, 256, 0, stream>>>(embedding_mean, psum, out3, nOut, out2, out4);
}